// Round 7
// baseline (168.660 us; speedup 1.0000x reference)
//
#include <hip/hip_runtime.h>
#include <hip/hip_bf16.h>
#include <cstdint>
#include <cstddef>

#define NN     50000
#define NE     800000
#define FIN    128
#define CAP    64       // per-node bucket capacity; P(Poisson(16)>64) ~ 5e-19
#define NBIN   784      // bins of 64 dst nodes: bin = dst>>6
#define CAPBIN 1280     // slots per bin segment; Poisson(1024)+6sigma ~ 1216
#define SB     157      // scatter blocks
#define EPT    20       // edges per thread in scatter (157*256*20 = 803840 >= NE)

using bf16x8 = __attribute__((ext_vector_type(8))) short;
using f32x4  = __attribute__((ext_vector_type(4))) float;

// ---- workspace layout ----
// int elements from (int*)d_ws
static const size_t OFF_CUR  = 0;          // int[784]  bincursor (final = bin counts)
static const size_t OFF_PART = 800;        // int[784*1280 = 1,003,520]
// short elements from (short*)d_ws  (int end 1,004,320 -> short 2,008,640)
static const size_t S_HB  = 2008640;       // bf16[6,400,000]
static const size_t S_HNB = 8408640;       // bf16[6,400,000]
static const size_t S_WB  = 14808640;      // bf16[32,768]
// end = 14,841,408 shorts = 29.7 MB

__device__ __forceinline__ unsigned f2bf(float f) {
    unsigned u = __float_as_uint(f);
    return (u + 0x7FFFu + ((u >> 16) & 1u)) >> 16;   // RNE
}

// ---- K1: convert h->bf16, W->bf16; one block zeros bincursor ----
__global__ void k_prep(const float* __restrict__ h, const float* __restrict__ W,
                       unsigned* __restrict__ hB, unsigned* __restrict__ WB,
                       int* __restrict__ bincursor) {
    int blk = blockIdx.x, tid = threadIdx.x;
    if (blk == 3141) {                     // zero block
        for (int t = tid; t < NBIN; t += 256) bincursor[t] = 0;
        return;
    }
    int i = blk * 256 + tid;               // [0, 804096)
    size_t e = (size_t)i * 8;
    const float* s;
    unsigned* d;
    if (e < 6400000) { s = h + e; d = hB + e / 2; }
    else if (e < 6400000 + 32768) { s = W + (e - 6400000); d = WB + (e - 6400000) / 2; }
    else return;
    float4 a = *(const float4*)s;
    float4 b = *(const float4*)(s + 4);
    uint4 o;
    o.x = f2bf(a.x) | (f2bf(a.y) << 16);
    o.y = f2bf(a.z) | (f2bf(a.w) << 16);
    o.z = f2bf(b.x) | (f2bf(b.y) << 16);
    o.w = f2bf(b.z) | (f2bf(b.w) << 16);
    *(uint4*)d = o;
}

// ---- K2: two-phase scatter into fixed bin segments ----
__global__ __launch_bounds__(256) void k_scatter(const int* __restrict__ src,
                                                 const int* __restrict__ dst,
                                                 int* __restrict__ bincursor,
                                                 int* __restrict__ part) {
    __shared__ int lcur[NBIN];
    __shared__ int lbase[NBIN];
    int tid = threadIdx.x, b = blockIdx.x;
    for (int t = tid; t < NBIN; t += 256) lcur[t] = 0;
    __syncthreads();
    int e0 = b * (EPT * 256);
    int pk[EPT], rk[EPT];
#pragma unroll
    for (int k = 0; k < EPT; ++k) {
        int e = e0 + k * 256 + tid;
        if (e < NE) {
            int d = dst[e];
            int s = src[e];
            int bin = d >> 6;
            pk[k] = s | ((d & 63) << 16) | (bin << 22);   // s:16 | local:6 | bin:10
            rk[k] = atomicAdd(&lcur[bin], 1);
        } else {
            pk[k] = -1;
        }
    }
    __syncthreads();
    for (int t = tid; t < NBIN; t += 256) {
        int c = lcur[t];
        lbase[t] = c ? atomicAdd(&bincursor[t], c) : 0;
    }
    __syncthreads();
#pragma unroll
    for (int k = 0; k < EPT; ++k) {
        if (pk[k] != -1) {
            int bin = ((unsigned)pk[k]) >> 22;
            int pos = lbase[bin] + rk[k];
            if (pos < CAPBIN)
                part[bin * CAPBIN + pos] = pk[k] & 0x3FFFFF;   // s | local<<16
        }
    }
}

// ---- K3: per-quarter-bin LDS bucket + gather-mean aggregation ----
// 4 blocks per bin; 2KB LDS -> 8 blocks/CU; ILP-16/8 gather for MLP.
__global__ __launch_bounds__(256) void k_aggbin(const int* __restrict__ part,
                                                const int* __restrict__ bincursor,
                                                const unsigned* __restrict__ hB2,
                                                unsigned* __restrict__ hNB2) {
    __shared__ int ldeg[16];
    __shared__ unsigned short bucketL[16 * CAP];   // 2 KB
    int blk = blockIdx.x, tid = threadIdx.x;
    int bin = blk >> 2, sub = blk & 3;
    if (tid < 16) ldeg[tid] = 0;
    __syncthreads();
    int cnt = min(bincursor[bin], CAPBIN);
    const int* pj = part + bin * CAPBIN;
    for (int i = tid; i < cnt; i += 256) {
        int v = pj[i];
        int local = (v >> 16) & 63;
        if ((local >> 4) == sub) {
            int l16 = local & 15;
            int slot = atomicAdd(&ldeg[l16], 1);
            if (slot < CAP) bucketL[l16 * CAP + slot] = (unsigned short)v;
        }
    }
    __syncthreads();
    int wave = tid >> 6, lane = tid & 63;
#pragma unroll
    for (int t = 0; t < 4; ++t) {
        int l16 = wave * 4 + t;
        int n = bin * 64 + (sub << 4) + l16;
        if (n >= NN) continue;
        int d = ldeg[l16];
        int c2 = min(d, CAP);
        int idx = (lane < c2) ? (int)bucketL[l16 * CAP + lane] : 0;
        float ax = 0.f, ay = 0.f;
        int i = 0;
        for (; i + 16 <= c2; i += 16) {
            unsigned v0 = hB2[(size_t)__shfl(idx, i     ) * 64 + lane];
            unsigned v1 = hB2[(size_t)__shfl(idx, i +  1) * 64 + lane];
            unsigned v2 = hB2[(size_t)__shfl(idx, i +  2) * 64 + lane];
            unsigned v3 = hB2[(size_t)__shfl(idx, i +  3) * 64 + lane];
            unsigned v4 = hB2[(size_t)__shfl(idx, i +  4) * 64 + lane];
            unsigned v5 = hB2[(size_t)__shfl(idx, i +  5) * 64 + lane];
            unsigned v6 = hB2[(size_t)__shfl(idx, i +  6) * 64 + lane];
            unsigned v7 = hB2[(size_t)__shfl(idx, i +  7) * 64 + lane];
            unsigned v8 = hB2[(size_t)__shfl(idx, i +  8) * 64 + lane];
            unsigned v9 = hB2[(size_t)__shfl(idx, i +  9) * 64 + lane];
            unsigned va = hB2[(size_t)__shfl(idx, i + 10) * 64 + lane];
            unsigned vb = hB2[(size_t)__shfl(idx, i + 11) * 64 + lane];
            unsigned vc = hB2[(size_t)__shfl(idx, i + 12) * 64 + lane];
            unsigned vd = hB2[(size_t)__shfl(idx, i + 13) * 64 + lane];
            unsigned ve = hB2[(size_t)__shfl(idx, i + 14) * 64 + lane];
            unsigned vf = hB2[(size_t)__shfl(idx, i + 15) * 64 + lane];
            ax += __uint_as_float(v0 << 16) + __uint_as_float(v1 << 16)
                + __uint_as_float(v2 << 16) + __uint_as_float(v3 << 16)
                + __uint_as_float(v4 << 16) + __uint_as_float(v5 << 16)
                + __uint_as_float(v6 << 16) + __uint_as_float(v7 << 16)
                + __uint_as_float(v8 << 16) + __uint_as_float(v9 << 16)
                + __uint_as_float(va << 16) + __uint_as_float(vb << 16)
                + __uint_as_float(vc << 16) + __uint_as_float(vd << 16)
                + __uint_as_float(ve << 16) + __uint_as_float(vf << 16);
            ay += __uint_as_float(v0 & 0xFFFF0000u) + __uint_as_float(v1 & 0xFFFF0000u)
                + __uint_as_float(v2 & 0xFFFF0000u) + __uint_as_float(v3 & 0xFFFF0000u)
                + __uint_as_float(v4 & 0xFFFF0000u) + __uint_as_float(v5 & 0xFFFF0000u)
                + __uint_as_float(v6 & 0xFFFF0000u) + __uint_as_float(v7 & 0xFFFF0000u)
                + __uint_as_float(v8 & 0xFFFF0000u) + __uint_as_float(v9 & 0xFFFF0000u)
                + __uint_as_float(va & 0xFFFF0000u) + __uint_as_float(vb & 0xFFFF0000u)
                + __uint_as_float(vc & 0xFFFF0000u) + __uint_as_float(vd & 0xFFFF0000u)
                + __uint_as_float(ve & 0xFFFF0000u) + __uint_as_float(vf & 0xFFFF0000u);
        }
        for (; i + 8 <= c2; i += 8) {
            unsigned v0 = hB2[(size_t)__shfl(idx, i    ) * 64 + lane];
            unsigned v1 = hB2[(size_t)__shfl(idx, i + 1) * 64 + lane];
            unsigned v2 = hB2[(size_t)__shfl(idx, i + 2) * 64 + lane];
            unsigned v3 = hB2[(size_t)__shfl(idx, i + 3) * 64 + lane];
            unsigned v4 = hB2[(size_t)__shfl(idx, i + 4) * 64 + lane];
            unsigned v5 = hB2[(size_t)__shfl(idx, i + 5) * 64 + lane];
            unsigned v6 = hB2[(size_t)__shfl(idx, i + 6) * 64 + lane];
            unsigned v7 = hB2[(size_t)__shfl(idx, i + 7) * 64 + lane];
            ax += __uint_as_float(v0 << 16) + __uint_as_float(v1 << 16)
                + __uint_as_float(v2 << 16) + __uint_as_float(v3 << 16)
                + __uint_as_float(v4 << 16) + __uint_as_float(v5 << 16)
                + __uint_as_float(v6 << 16) + __uint_as_float(v7 << 16);
            ay += __uint_as_float(v0 & 0xFFFF0000u) + __uint_as_float(v1 & 0xFFFF0000u)
                + __uint_as_float(v2 & 0xFFFF0000u) + __uint_as_float(v3 & 0xFFFF0000u)
                + __uint_as_float(v4 & 0xFFFF0000u) + __uint_as_float(v5 & 0xFFFF0000u)
                + __uint_as_float(v6 & 0xFFFF0000u) + __uint_as_float(v7 & 0xFFFF0000u);
        }
        for (; i < c2; ++i) {
            unsigned v = hB2[(size_t)__shfl(idx, i) * 64 + lane];
            ax += __uint_as_float(v << 16);
            ay += __uint_as_float(v & 0xFFFF0000u);
        }
        float inv = 1.0f / fmaxf((float)d, 1.0f);
        hNB2[(size_t)n * 64 + lane] = f2bf(ax * inv) | (f2bf(ay * inv) << 16);
    }
}

// ---- K4: out = [hB | hNB] @ W^T + b, register-resident W, zero LDS ----
// Block = 4 waves; wave w: nodes [blk*32 + (w>>1)*16, +16), jhalf = w&1.
// Per wave: bw[4][8] = 128 VGPR of W frags, 32 MFMAs, no barriers.
__global__ __launch_bounds__(256) void k_gemm(
    const short* __restrict__ hB, const short* __restrict__ hNB,
    const short* __restrict__ WB, const float* __restrict__ bias,
    float* __restrict__ out)
{
    const int tid  = threadIdx.x;
    const int wave = tid >> 6;
    const int lane = tid & 63;
    const int q    = lane >> 4;
    const int ln   = lane & 15;
    const int mbase = blockIdx.x * 32 + (wave >> 1) * 16;
    const int jbase = (wave & 1) * 64;
    int node = mbase + ln;
    if (node >= NN) node = NN - 1;

    // B fragments: lane(q,ln) holds W[jbase+t*16+ln][(k0*4+q)*8 .. +8]
    bf16x8 bw[4][8];
#pragma unroll
    for (int t = 0; t < 4; ++t) {
        const short* wr = WB + (size_t)(jbase + t * 16 + ln) * 256 + q * 8;
#pragma unroll
        for (int k0 = 0; k0 < 8; ++k0)
            bw[t][k0] = *(const bf16x8*)(wr + k0 * 32);
    }

    f32x4 acc[4];
#pragma unroll
    for (int t = 0; t < 4; ++t) acc[t] = (f32x4){0.f, 0.f, 0.f, 0.f};

#pragma unroll
    for (int k0 = 0; k0 < 8; ++k0) {
        int ck = k0 * 4 + q;
        const short* ap = (k0 < 4) ? (hB  + (size_t)node * 128 + ck * 8)
                                   : (hNB + (size_t)node * 128 + (ck - 16) * 8);
        bf16x8 afr = *(const bf16x8*)ap;
#pragma unroll
        for (int t = 0; t < 4; ++t)
            acc[t] = __builtin_amdgcn_mfma_f32_16x16x32_bf16(afr, bw[t][k0], acc[t], 0, 0, 0);
    }

#pragma unroll
    for (int t = 0; t < 4; ++t) {
        float bv = bias[jbase + t * 16 + ln];
#pragma unroll
        for (int r = 0; r < 4; ++r) {
            int m = mbase + q * 4 + r;
            if (m < NN)
                out[(size_t)m * FIN + jbase + t * 16 + ln] = acc[t][r] + bv;
        }
    }
}

extern "C" void kernel_launch(void* const* d_in, const int* in_sizes, int n_in,
                              void* d_out, int out_size, void* d_ws, size_t ws_size,
                              hipStream_t stream) {
    const float* h   = (const float*)d_in[0];
    const int*   src = (const int*)d_in[1];
    const int*   dst = (const int*)d_in[2];
    const float* W   = (const float*)d_in[3];
    const float* b   = (const float*)d_in[4];
    float* out = (float*)d_out;

    int*   wsI = (int*)d_ws;
    short* wsS = (short*)d_ws;

    int* bincursor = wsI + OFF_CUR;
    int* part      = wsI + OFF_PART;
    short* hB      = wsS + S_HB;
    short* hNB     = wsS + S_HNB;
    short* WB      = wsS + S_WB;

    k_prep   <<<3142, 256, 0, stream>>>(h, W, (unsigned*)hB, (unsigned*)WB, bincursor);
    k_scatter<<<SB, 256, 0, stream>>>(src, dst, bincursor, part);
    k_aggbin <<<NBIN * 4, 256, 0, stream>>>(part, bincursor,
                                            (const unsigned*)hB, (unsigned*)hNB);
    k_gemm   <<<(NN + 31) / 32, 256, 0, stream>>>(hB, hNB, WB, b, out);
}

// Round 8
// 150.793 us; speedup vs baseline: 1.1185x; 1.1185x over previous
//
#include <hip/hip_runtime.h>
#include <hip/hip_bf16.h>
#include <cstdint>
#include <cstddef>

#define NN     50000
#define NE     800000
#define FIN    128
#define CAP    64       // per-node bucket capacity; P(Poisson(16)>64) ~ 5e-19
#define NBIN   784      // bins of 64 dst nodes: bin = dst>>6
#define CAPBIN 1280     // slots per bin segment; Poisson(1024)+6sigma ~ 1216
#define SB     157      // scatter blocks
#define EPT    20       // edges per thread in scatter (157*256*20 = 803840 >= NE)

using bf16x8 = __attribute__((ext_vector_type(8))) short;
using f32x4  = __attribute__((ext_vector_type(4))) float;

// ---- workspace layout ----
// int elements from (int*)d_ws
static const size_t OFF_CUR  = 0;          // int[784]  bincursor (final = bin counts)
static const size_t OFF_PART = 800;        // int[784*1280 = 1,003,520]
// short elements from (short*)d_ws  (int end 1,004,320 -> short 2,008,640)
static const size_t S_HB  = 2008640;       // bf16[6,400,000]
static const size_t S_HNB = 8408640;       // bf16[6,400,000]
static const size_t S_WB  = 14808640;      // bf16[32,768]
// end = 14,841,408 shorts = 29.7 MB

__device__ __forceinline__ unsigned f2bf(float f) {
    unsigned u = __float_as_uint(f);
    return (u + 0x7FFFu + ((u >> 16) & 1u)) >> 16;   // RNE
}

// ---- K1: convert h->bf16, W->bf16; one block zeros bincursor ----
__global__ void k_prep(const float* __restrict__ h, const float* __restrict__ W,
                       unsigned* __restrict__ hB, unsigned* __restrict__ WB,
                       int* __restrict__ bincursor) {
    int blk = blockIdx.x, tid = threadIdx.x;
    if (blk == 3141) {                     // zero block
        for (int t = tid; t < NBIN; t += 256) bincursor[t] = 0;
        return;
    }
    int i = blk * 256 + tid;               // [0, 804096)
    size_t e = (size_t)i * 8;
    const float* s;
    unsigned* d;
    if (e < 6400000) { s = h + e; d = hB + e / 2; }
    else if (e < 6400000 + 32768) { s = W + (e - 6400000); d = WB + (e - 6400000) / 2; }
    else return;
    float4 a = *(const float4*)s;
    float4 b = *(const float4*)(s + 4);
    uint4 o;
    o.x = f2bf(a.x) | (f2bf(a.y) << 16);
    o.y = f2bf(a.z) | (f2bf(a.w) << 16);
    o.z = f2bf(b.x) | (f2bf(b.y) << 16);
    o.w = f2bf(b.z) | (f2bf(b.w) << 16);
    *(uint4*)d = o;
}

// ---- K2: two-phase scatter into fixed bin segments ----
__global__ __launch_bounds__(256) void k_scatter(const int* __restrict__ src,
                                                 const int* __restrict__ dst,
                                                 int* __restrict__ bincursor,
                                                 int* __restrict__ part) {
    __shared__ int lcur[NBIN];
    __shared__ int lbase[NBIN];
    int tid = threadIdx.x, b = blockIdx.x;
    for (int t = tid; t < NBIN; t += 256) lcur[t] = 0;
    __syncthreads();
    int e0 = b * (EPT * 256);
    int pk[EPT], rk[EPT];
#pragma unroll
    for (int k = 0; k < EPT; ++k) {
        int e = e0 + k * 256 + tid;
        if (e < NE) {
            int d = dst[e];
            int s = src[e];
            int bin = d >> 6;
            pk[k] = s | ((d & 63) << 16) | (bin << 22);   // s:16 | local:6 | bin:10
            rk[k] = atomicAdd(&lcur[bin], 1);
        } else {
            pk[k] = -1;
        }
    }
    __syncthreads();
    for (int t = tid; t < NBIN; t += 256) {
        int c = lcur[t];
        lbase[t] = c ? atomicAdd(&bincursor[t], c) : 0;
    }
    __syncthreads();
#pragma unroll
    for (int k = 0; k < EPT; ++k) {
        if (pk[k] != -1) {
            int bin = ((unsigned)pk[k]) >> 22;
            int pos = lbase[bin] + rk[k];
            if (pos < CAPBIN)
                part[bin * CAPBIN + pos] = pk[k] & 0x3FFFFF;   // s | local<<16
        }
    }
}

// ---- K3: per-quarter-bin LDS bucket + gather-mean aggregation ----
// 4 blocks per bin; 2KB LDS -> 8 blocks/CU; ILP-16/8 gather.
__global__ __launch_bounds__(256) void k_aggbin(const int* __restrict__ part,
                                                const int* __restrict__ bincursor,
                                                const unsigned* __restrict__ hB2,
                                                unsigned* __restrict__ hNB2) {
    __shared__ int ldeg[16];
    __shared__ unsigned short bucketL[16 * CAP];   // 2 KB
    int blk = blockIdx.x, tid = threadIdx.x;
    int bin = blk >> 2, sub = blk & 3;
    if (tid < 16) ldeg[tid] = 0;
    __syncthreads();
    int cnt = min(bincursor[bin], CAPBIN);
    const int* pj = part + bin * CAPBIN;
    for (int i = tid; i < cnt; i += 256) {
        int v = pj[i];
        int local = (v >> 16) & 63;
        if ((local >> 4) == sub) {
            int l16 = local & 15;
            int slot = atomicAdd(&ldeg[l16], 1);
            if (slot < CAP) bucketL[l16 * CAP + slot] = (unsigned short)v;
        }
    }
    __syncthreads();
    int wave = tid >> 6, lane = tid & 63;
#pragma unroll
    for (int t = 0; t < 4; ++t) {
        int l16 = wave * 4 + t;
        int n = bin * 64 + (sub << 4) + l16;
        if (n >= NN) continue;
        int d = ldeg[l16];
        int c2 = min(d, CAP);
        int idx = (lane < c2) ? (int)bucketL[l16 * CAP + lane] : 0;
        float ax = 0.f, ay = 0.f;
        int i = 0;
        for (; i + 16 <= c2; i += 16) {
            unsigned v0 = hB2[(size_t)__shfl(idx, i     ) * 64 + lane];
            unsigned v1 = hB2[(size_t)__shfl(idx, i +  1) * 64 + lane];
            unsigned v2 = hB2[(size_t)__shfl(idx, i +  2) * 64 + lane];
            unsigned v3 = hB2[(size_t)__shfl(idx, i +  3) * 64 + lane];
            unsigned v4 = hB2[(size_t)__shfl(idx, i +  4) * 64 + lane];
            unsigned v5 = hB2[(size_t)__shfl(idx, i +  5) * 64 + lane];
            unsigned v6 = hB2[(size_t)__shfl(idx, i +  6) * 64 + lane];
            unsigned v7 = hB2[(size_t)__shfl(idx, i +  7) * 64 + lane];
            unsigned v8 = hB2[(size_t)__shfl(idx, i +  8) * 64 + lane];
            unsigned v9 = hB2[(size_t)__shfl(idx, i +  9) * 64 + lane];
            unsigned va = hB2[(size_t)__shfl(idx, i + 10) * 64 + lane];
            unsigned vb = hB2[(size_t)__shfl(idx, i + 11) * 64 + lane];
            unsigned vc = hB2[(size_t)__shfl(idx, i + 12) * 64 + lane];
            unsigned vd = hB2[(size_t)__shfl(idx, i + 13) * 64 + lane];
            unsigned ve = hB2[(size_t)__shfl(idx, i + 14) * 64 + lane];
            unsigned vf = hB2[(size_t)__shfl(idx, i + 15) * 64 + lane];
            ax += __uint_as_float(v0 << 16) + __uint_as_float(v1 << 16)
                + __uint_as_float(v2 << 16) + __uint_as_float(v3 << 16)
                + __uint_as_float(v4 << 16) + __uint_as_float(v5 << 16)
                + __uint_as_float(v6 << 16) + __uint_as_float(v7 << 16)
                + __uint_as_float(v8 << 16) + __uint_as_float(v9 << 16)
                + __uint_as_float(va << 16) + __uint_as_float(vb << 16)
                + __uint_as_float(vc << 16) + __uint_as_float(vd << 16)
                + __uint_as_float(ve << 16) + __uint_as_float(vf << 16);
            ay += __uint_as_float(v0 & 0xFFFF0000u) + __uint_as_float(v1 & 0xFFFF0000u)
                + __uint_as_float(v2 & 0xFFFF0000u) + __uint_as_float(v3 & 0xFFFF0000u)
                + __uint_as_float(v4 & 0xFFFF0000u) + __uint_as_float(v5 & 0xFFFF0000u)
                + __uint_as_float(v6 & 0xFFFF0000u) + __uint_as_float(v7 & 0xFFFF0000u)
                + __uint_as_float(v8 & 0xFFFF0000u) + __uint_as_float(v9 & 0xFFFF0000u)
                + __uint_as_float(va & 0xFFFF0000u) + __uint_as_float(vb & 0xFFFF0000u)
                + __uint_as_float(vc & 0xFFFF0000u) + __uint_as_float(vd & 0xFFFF0000u)
                + __uint_as_float(ve & 0xFFFF0000u) + __uint_as_float(vf & 0xFFFF0000u);
        }
        for (; i + 8 <= c2; i += 8) {
            unsigned v0 = hB2[(size_t)__shfl(idx, i    ) * 64 + lane];
            unsigned v1 = hB2[(size_t)__shfl(idx, i + 1) * 64 + lane];
            unsigned v2 = hB2[(size_t)__shfl(idx, i + 2) * 64 + lane];
            unsigned v3 = hB2[(size_t)__shfl(idx, i + 3) * 64 + lane];
            unsigned v4 = hB2[(size_t)__shfl(idx, i + 4) * 64 + lane];
            unsigned v5 = hB2[(size_t)__shfl(idx, i + 5) * 64 + lane];
            unsigned v6 = hB2[(size_t)__shfl(idx, i + 6) * 64 + lane];
            unsigned v7 = hB2[(size_t)__shfl(idx, i + 7) * 64 + lane];
            ax += __uint_as_float(v0 << 16) + __uint_as_float(v1 << 16)
                + __uint_as_float(v2 << 16) + __uint_as_float(v3 << 16)
                + __uint_as_float(v4 << 16) + __uint_as_float(v5 << 16)
                + __uint_as_float(v6 << 16) + __uint_as_float(v7 << 16);
            ay += __uint_as_float(v0 & 0xFFFF0000u) + __uint_as_float(v1 & 0xFFFF0000u)
                + __uint_as_float(v2 & 0xFFFF0000u) + __uint_as_float(v3 & 0xFFFF0000u)
                + __uint_as_float(v4 & 0xFFFF0000u) + __uint_as_float(v5 & 0xFFFF0000u)
                + __uint_as_float(v6 & 0xFFFF0000u) + __uint_as_float(v7 & 0xFFFF0000u);
        }
        for (; i < c2; ++i) {
            unsigned v = hB2[(size_t)__shfl(idx, i) * 64 + lane];
            ax += __uint_as_float(v << 16);
            ay += __uint_as_float(v & 0xFFFF0000u);
        }
        float inv = 1.0f / fmaxf((float)d, 1.0f);
        hNB2[(size_t)n * 64 + lane] = f2bf(ax * inv) | (f2bf(ay * inv) << 16);
    }
}

// ---- K4: out = [hB | hNB] @ W^T + b via MFMA, LDS-staged W, j-split ----
// blockIdx.y = j-half; LDS = 64 rows x 256 k bf16 = 32 KB -> 5 blocks/CU.
// Wave: 16 nodes x 64 outs, 32 ds_read_b128 + 32 MFMA. Swizzle: chunk c at (c+row)&31.
__global__ __launch_bounds__(256) void k_gemm(
    const short* __restrict__ hB, const short* __restrict__ hNB,
    const short* __restrict__ WB, const float* __restrict__ bias,
    float* __restrict__ out)
{
    __shared__ short WL[16384];   // 32 KB
    const int tid = threadIdx.x;
    const int jbase = blockIdx.y * 64;

    // stage W rows [jbase, jbase+64): 2048 chunks of 16B
    for (int g = tid; g < 2048; g += 256) {
        int row = g >> 5;          // 0..63
        int c   = g & 31;          // k-chunk
        int cs  = (c + row) & 31;  // swizzled
        bf16x8 v = *(const bf16x8*)(WB + (size_t)(jbase + row) * 256 + c * 8);
        *(bf16x8*)(&WL[row * 256 + cs * 8]) = v;
    }
    __syncthreads();

    const int wave = tid >> 6;
    const int lane = tid & 63;
    const int q    = lane >> 4;
    const int ln   = lane & 15;
    const int mbase = (blockIdx.x * 4 + wave) * 16;
    int node = mbase + ln;
    if (node >= NN) node = NN - 1;

    f32x4 acc[4];
#pragma unroll
    for (int t = 0; t < 4; ++t) acc[t] = (f32x4){0.f, 0.f, 0.f, 0.f};

#pragma unroll
    for (int k0 = 0; k0 < 8; ++k0) {
        int ck = k0 * 4 + q;
        const short* ap = (k0 < 4) ? (hB  + (size_t)node * 128 + ck * 8)
                                   : (hNB + (size_t)node * 128 + (ck - 16) * 8);
        bf16x8 afr = *(const bf16x8*)ap;
#pragma unroll
        for (int t = 0; t < 4; ++t) {
            int row = t * 16 + ln;
            int cs  = (ck + row) & 31;
            bf16x8 bfr = *(const bf16x8*)(&WL[row * 256 + cs * 8]);
            acc[t] = __builtin_amdgcn_mfma_f32_16x16x32_bf16(afr, bfr, acc[t], 0, 0, 0);
        }
    }

#pragma unroll
    for (int t = 0; t < 4; ++t) {
        float bv = bias[jbase + t * 16 + ln];
#pragma unroll
        for (int r = 0; r < 4; ++r) {
            int m = mbase + q * 4 + r;
            if (m < NN)
                out[(size_t)m * FIN + jbase + t * 16 + ln] = acc[t][r] + bv;
        }
    }
}

extern "C" void kernel_launch(void* const* d_in, const int* in_sizes, int n_in,
                              void* d_out, int out_size, void* d_ws, size_t ws_size,
                              hipStream_t stream) {
    const float* h   = (const float*)d_in[0];
    const int*   src = (const int*)d_in[1];
    const int*   dst = (const int*)d_in[2];
    const float* W   = (const float*)d_in[3];
    const float* b   = (const float*)d_in[4];
    float* out = (float*)d_out;

    int*   wsI = (int*)d_ws;
    short* wsS = (short*)d_ws;

    int* bincursor = wsI + OFF_CUR;
    int* part      = wsI + OFF_PART;
    short* hB      = wsS + S_HB;
    short* hNB     = wsS + S_HNB;
    short* WB      = wsS + S_WB;

    k_prep   <<<3142, 256, 0, stream>>>(h, W, (unsigned*)hB, (unsigned*)WB, bincursor);
    k_scatter<<<SB, 256, 0, stream>>>(src, dst, bincursor, part);
    k_aggbin <<<NBIN * 4, 256, 0, stream>>>(part, bincursor,
                                            (const unsigned*)hB, (unsigned*)hNB);
    k_gemm   <<<dim3((NN + 63) / 64, 2), 256, 0, stream>>>(hB, hNB, WB, b, out);
}